// Round 1
// baseline (879.309 us; speedup 1.0000x reference)
//
#include <hip/hip_runtime.h>
#include <math.h>

#define B       32
#define S_FULL  512
#define S       511            // sliced length (drop token 0)
#define D       768
#define NROWS   (B * S)        // 16352

#define TM 64
#define TN 64
#define TK 32

// ---------------- block reduce (256 threads, wave64) ----------------
__device__ inline float blockReduceSum256(float v) {
    #pragma unroll
    for (int off = 32; off > 0; off >>= 1) v += __shfl_down(v, off, 64);
    __shared__ float ls[4];
    int lane = threadIdx.x & 63;
    int w    = threadIdx.x >> 6;
    if (lane == 0) ls[w] = v;
    __syncthreads();
    float r = 0.f;
    if (threadIdx.x == 0) r = ls[0] + ls[1] + ls[2] + ls[3];
    return r;  // valid on thread 0 only
}

// ---------------- 1. row inverse norms ----------------
// grid: (NROWS, 2): y==0 -> text rows, y==1 -> target rows
__global__ __launch_bounds__(256) void norm_kernel(
    const float* __restrict__ text, const float* __restrict__ target,
    float* __restrict__ inv_t, float* __restrict__ inv_g)
{
    int row   = blockIdx.x;            // 0..NROWS-1
    int which = blockIdx.y;
    int b = row / S, i = row % S;
    const float* p = (which ? target : text) + (size_t)(b * S_FULL + i + 1) * D;
    float s = 0.f;
    for (int d = threadIdx.x; d < D; d += 256) { float v = p[d]; s += v * v; }
    s = blockReduceSum256(s);
    if (threadIdx.x == 0) {
        float inv = (s > 0.f) ? (1.0f / sqrtf(s)) : 0.f;
        (which ? inv_g : inv_t)[row] = inv;
    }
}

// ---------------- 2. tiled fp32 GEMM + running argmax ----------------
// grid: (ceil(S/TM)=8, B). block computes sim rows [i0,i0+64) vs all j, tracks argmax.
__global__ __launch_bounds__(256) void simargmax_kernel(
    const float* __restrict__ text, const float* __restrict__ target,
    const float* __restrict__ inv_t, const float* __restrict__ inv_g,
    int* __restrict__ idx_out, float* __restrict__ idx_out_f)
{
    __shared__ float As[TK * TM];   // [k][m]
    __shared__ float Bs[TK * TN];   // [k][n]
    __shared__ float redV[TM * 16];
    __shared__ int   redI[TM * 16];

    const int b   = blockIdx.y;
    const int i0  = blockIdx.x * TM;
    const int tid = threadIdx.x;
    const int tx  = tid & 15;       // col group (4 cols each)
    const int ty  = tid >> 4;       // row group (4 rows each)

    const float* Abase = text   + (size_t)b * S_FULL * D + D;   // +D: slice off token 0
    const float* Bbase = target + (size_t)b * S_FULL * D + D;
    const float* invTb = inv_t + b * S;
    const float* invGb = inv_g + b * S;

    float rmax[4] = {-INFINITY, -INFINITY, -INFINITY, -INFINITY};
    int   ridx[4] = {0, 0, 0, 0};

    const int srow = tid >> 3;          // 0..31 (staging row, +32 for second half)
    const int skk  = (tid & 7) * 4;     // 0..28 (staging k offset, float4)

    for (int j0 = 0; j0 < S; j0 += TN) {
        float acc[4][4];
        #pragma unroll
        for (int r = 0; r < 4; ++r)
            #pragma unroll
            for (int c = 0; c < 4; ++c) acc[r][c] = 0.f;

        for (int k0 = 0; k0 < D; k0 += TK) {
            __syncthreads();   // previous tile fully consumed
            #pragma unroll
            for (int h = 0; h < 2; ++h) {
                int row = srow + h * 32;
                // A tile (text rows, normalized on stage)
                int gi = i0 + row;
                float4 va = make_float4(0.f, 0.f, 0.f, 0.f);
                float  ia = 0.f;
                if (gi < S) {
                    va = *(const float4*)(Abase + (size_t)gi * D + k0 + skk);
                    ia = invTb[gi];
                }
                As[(skk + 0) * TM + row] = va.x * ia;
                As[(skk + 1) * TM + row] = va.y * ia;
                As[(skk + 2) * TM + row] = va.z * ia;
                As[(skk + 3) * TM + row] = va.w * ia;
                // B tile (target rows, normalized on stage)
                int gj = j0 + row;
                float4 vb = make_float4(0.f, 0.f, 0.f, 0.f);
                float  ib = 0.f;
                if (gj < S) {
                    vb = *(const float4*)(Bbase + (size_t)gj * D + k0 + skk);
                    ib = invGb[gj];
                }
                Bs[(skk + 0) * TN + row] = vb.x * ib;
                Bs[(skk + 1) * TN + row] = vb.y * ib;
                Bs[(skk + 2) * TN + row] = vb.z * ib;
                Bs[(skk + 3) * TN + row] = vb.w * ib;
            }
            __syncthreads();
            #pragma unroll
            for (int k = 0; k < TK; ++k) {
                const float4 a4 = *(const float4*)&As[k * TM + (ty << 2)];
                const float4 b4 = *(const float4*)&Bs[k * TN + (tx << 2)];
                float av[4] = {a4.x, a4.y, a4.z, a4.w};
                float bv[4] = {b4.x, b4.y, b4.z, b4.w};
                #pragma unroll
                for (int r = 0; r < 4; ++r)
                    #pragma unroll
                    for (int c = 0; c < 4; ++c)
                        acc[r][c] = fmaf(av[r], bv[c], acc[r][c]);
            }
        }

        // epilogue: fold this j-tile into running (max, first-idx)
        #pragma unroll
        for (int c = 0; c < 4; ++c) {
            int j = j0 + (tx << 2) + c;
            if (j < S) {
                #pragma unroll
                for (int r = 0; r < 4; ++r) {
                    float v = acc[r][c];
                    if (v > rmax[r]) { rmax[r] = v; ridx[r] = j; }  // strict > keeps first occurrence
                }
            }
        }
    }

    // cross-thread argmax reduce (16 tx candidates per row)
    __syncthreads();
    #pragma unroll
    for (int r = 0; r < 4; ++r) {
        int m = (ty << 2) + r;
        redV[m * 16 + tx] = rmax[r];
        redI[m * 16 + tx] = ridx[r];
    }
    __syncthreads();
    if (tid < TM) {
        int m = tid;
        float best = redV[m * 16];
        int   bid  = redI[m * 16];
        for (int t = 1; t < 16; ++t) {
            float v  = redV[m * 16 + t];
            int   id = redI[m * 16 + t];
            if (v > best || (v == best && id < bid)) { best = v; bid = id; }
        }
        int gi = i0 + m;
        if (gi < S) {
            idx_out[b * S + gi]   = bid;
            idx_out_f[b * S + gi] = (float)bid;
        }
    }
}

// ---------------- 3. image loss: sum((image-target)^2) ----------------
__global__ __launch_bounds__(256) void image_loss_kernel(
    const float* __restrict__ image, const float* __restrict__ target,
    float* __restrict__ accum)
{
    const size_t n4 = (size_t)B * S_FULL * D / 4;
    float s = 0.f;
    for (size_t i = (size_t)blockIdx.x * 256 + threadIdx.x; i < n4;
         i += (size_t)gridDim.x * 256) {
        float4 a = ((const float4*)image)[i];
        float4 t = ((const float4*)target)[i];
        float dx = a.x - t.x, dy = a.y - t.y, dz = a.z - t.z, dw = a.w - t.w;
        s += dx * dx + dy * dy + dz * dz + dw * dw;
    }
    s = blockReduceSum256(s);
    if (threadIdx.x == 0) atomicAdd(&accum[0], s);
}

// ---------------- 4. text loss: sum((txt - tgt[idx])^2 * valid) ----------------
// grid: NROWS blocks
__global__ __launch_bounds__(256) void text_loss_kernel(
    const float* __restrict__ text, const float* __restrict__ target,
    const int* __restrict__ pm, const int* __restrict__ idx,
    float* __restrict__ accum)
{
    int row = blockIdx.x;
    int b = row / S, i = row % S;
    if (pm[b * S_FULL + i + 1] != 0) return;   // uniform across block
    int j = idx[row];
    const float* t = text   + (size_t)(b * S_FULL + i + 1) * D;
    const float* g = target + (size_t)(b * S_FULL + j + 1) * D;
    float s = 0.f;
    for (int d = threadIdx.x; d < D; d += 256) {
        float df = t[d] - g[d];
        s += df * df;
    }
    s = blockReduceSum256(s);
    if (threadIdx.x == 0) {
        atomicAdd(&accum[1], s);
        atomicAdd(&accum[2], 1.0f);
    }
}

// ---------------- 5. finalize ----------------
__global__ void finalize_kernel(const float* __restrict__ accum, float* __restrict__ out)
{
    if (threadIdx.x == 0 && blockIdx.x == 0) {
        float img = accum[0] / (float)((size_t)B * S_FULL * D);
        float txt = accum[1] / (accum[2] * (float)D);
        out[0] = 0.5f * (txt + img);
        out[1] = txt;
        out[2] = img;
    }
}

extern "C" void kernel_launch(void* const* d_in, const int* in_sizes, int n_in,
                              void* d_out, int out_size, void* d_ws, size_t ws_size,
                              hipStream_t stream) {
    const float* image  = (const float*)d_in[0];
    const float* text   = (const float*)d_in[1];
    const float* target = (const float*)d_in[2];
    const int*   pm     = (const int*)d_in[3];
    float* out = (float*)d_out;

    float* ws     = (float*)d_ws;
    float* inv_t  = ws;                       // NROWS floats
    float* inv_g  = ws + NROWS;               // NROWS floats
    int*   idxbuf = (int*)(ws + 2 * NROWS);   // NROWS ints
    float* accum  = ws + 3 * NROWS;           // [img_sum, txt_sum, valid_cnt]

    hipMemsetAsync(accum, 0, 3 * sizeof(float), stream);

    norm_kernel<<<dim3(NROWS, 2), 256, 0, stream>>>(text, target, inv_t, inv_g);
    simargmax_kernel<<<dim3((S + TM - 1) / TM, B), 256, 0, stream>>>(
        text, target, inv_t, inv_g, idxbuf, out + 3);
    image_loss_kernel<<<2048, 256, 0, stream>>>(image, target, accum);
    text_loss_kernel<<<NROWS, 256, 0, stream>>>(text, target, pm, idxbuf, accum);
    finalize_kernel<<<1, 64, 0, stream>>>(accum, out);
}